// Round 4
// baseline (169.209 us; speedup 1.0000x reference)
//
#include <hip/hip_runtime.h>
#include <hip/hip_bf16.h>

typedef short s16x8 __attribute__((ext_vector_type(8)));
typedef float f32x4 __attribute__((ext_vector_type(4)));
typedef unsigned short u16x8 __attribute__((ext_vector_type(8)));

__device__ __forceinline__ unsigned short f2bf(float f) {
  union { __hip_bfloat16 h; unsigned short u; } cv;
  cv.h = __float2bfloat16(f);
  return cv.u;
}
__device__ __forceinline__ float bf2f(unsigned short u) {
  union { unsigned int i; float f; } cv;
  cv.i = ((unsigned int)u) << 16;
  return cv.f;
}

__device__ __forceinline__ void gload_lds16(const void* g, void* l) {
  __builtin_amdgcn_global_load_lds(
      (const __attribute__((address_space(1))) unsigned int*)g,
      (__attribute__((address_space(3))) unsigned int*)l,
      16, 0, 0);
}

// One-shot f32->bf16 cast of three buffers (G, Wk, Wq), float4-vectorized.
__global__ __launch_bounds__(256) void cast3_bf16(
    const float* __restrict__ a, unsigned short* __restrict__ da, int n4a,
    const float* __restrict__ b, unsigned short* __restrict__ db, int n4b,
    const float* __restrict__ c, unsigned short* __restrict__ dc, int n4c) {
  const int total = n4a + n4b + n4c;
  for (int i = blockIdx.x * 256 + threadIdx.x; i < total; i += gridDim.x * 256) {
    const float* s; unsigned short* d; int j = i;
    if (j < n4a) { s = a; d = da; }
    else if ((j -= n4a) < n4b) { s = b; d = db; }
    else { j -= n4b; s = c; d = dc; }
    float4 v = *(const float4*)(s + (size_t)j * 4);
    ushort4 o;
    o.x = f2bf(v.x); o.y = f2bf(v.y); o.z = f2bf(v.z); o.w = f2bf(v.w);
    *(ushort4*)(d + (size_t)j * 4) = o;
  }
}

// Per-batch compaction scan: keep[l] = (mask[l]==0).
__global__ __launch_bounds__(256) void mask_scan(
    const int* __restrict__ mask, int* __restrict__ idx,
    int* __restrict__ Lc, int* __restrict__ Lcp) {
  const int b = blockIdx.x;
  const int* mb = mask + (size_t)b * 2048;
  int* ib = idx + (size_t)b * 2048;
  const int t = threadIdx.x;
  __shared__ int tot[256];
  __shared__ int off[257];
  int keep[8], cnt = 0;
#pragma unroll
  for (int j = 0; j < 8; ++j) {
    keep[j] = (mb[t * 8 + j] == 0);
    cnt += keep[j];
  }
  tot[t] = cnt;
  __syncthreads();
  if (t == 0) {
    int s = 0;
    for (int i = 0; i < 256; ++i) { off[i] = s; s += tot[i]; }
    off[256] = s;
  }
  __syncthreads();
  int p = off[t];
#pragma unroll
  for (int j = 0; j < 8; ++j)
    if (keep[j]) ib[p++] = t * 8 + j;
  if (t == 0) {
    Lc[b] = off[256];
    Lcp[b] = (off[256] + 127) & ~127;
  }
}

// Gather unmasked H rows (f32) -> Hc (B, L, Dh) bf16 row-major AND
// HcT (B, Dh, L) bf16 transposed. Rows [Lc, Lcp) zero-filled.
__global__ __launch_bounds__(256) void gather_cast(
    const float* __restrict__ H, const int* __restrict__ idx,
    const int* __restrict__ Lc, const int* __restrict__ Lcp,
    unsigned short* __restrict__ Hc, unsigned short* __restrict__ HcT) {
  const int b = blockIdx.z;
  const int j0 = blockIdx.x * 64, d0 = blockIdx.y * 64;
  if (j0 >= Lcp[b]) return;
  const int lc = Lc[b];
  __shared__ unsigned short tile[64][72];
  const int t = threadIdx.x;

  const int r = t >> 2, dc = (t & 3) * 16;
  const int j = j0 + r;
  const int src = (j < lc) ? idx[(size_t)b * 2048 + j] : -1;
  ushort4 s[4];
  if (src >= 0) {
    const float* p = H + ((size_t)b * 2048 + src) * 1024 + d0 + dc;
#pragma unroll
    for (int i = 0; i < 4; ++i) {
      float4 v = *(const float4*)(p + 4 * i);
      s[i].x = f2bf(v.x); s[i].y = f2bf(v.y); s[i].z = f2bf(v.z); s[i].w = f2bf(v.w);
    }
  } else {
#pragma unroll
    for (int i = 0; i < 4; ++i) { s[i].x = 0; s[i].y = 0; s[i].z = 0; s[i].w = 0; }
  }
  unsigned short* hcrow = Hc + ((size_t)b * 2048 + j) * 1024 + d0 + dc;
#pragma unroll
  for (int i = 0; i < 4; ++i) {
    *(ushort4*)&tile[r][dc + 4 * i] = s[i];
    *(ushort4*)(hcrow + 4 * i) = s[i];
  }
  __syncthreads();

  const int dr = t >> 2, lcc = (t & 3) * 16;
  unsigned short o[16];
#pragma unroll
  for (int i = 0; i < 16; ++i) o[i] = tile[lcc + i][dr];
  unsigned short* dst = HcT + ((size_t)b * 1024 + d0 + dr) * 2048 + j0 + lcc;
  *(uint4*)dst = *(uint4*)&o[0];
  *(uint4*)(dst + 8) = *(uint4*)&o[8];
}

// C (M x N tile 128 x BN) = A (M x K) * B^T, bf16 in via global_load_lds.
// MODE 0: plain 3D grid (x=bn, y=bm, z=b), full K, optional mExt/nExt exits.
// MODE 1: score swizzle. 1D grid of 1024; XCD-chunked: each XCD gets one
//         batch (within-batch 128 blocks = bm*16+bn, bm in [0,8), bn in [0,16)).
// MODE 2: PV split-K=2 + swizzle. 1D grid of 1024; each XCD gets one
//         (batch, K-half) then the other; inner 64 = bm*8+bn. f32 atomicAdd.
template <int BN, bool OUT_BF16, int MODE>
__global__ __launch_bounds__(256) void gemm_bt(
    const unsigned short* __restrict__ Ag, const unsigned short* __restrict__ Bg,
    void* __restrict__ Cg_, int N, int Kfix, int lda, int ldb, float scale,
    long long strideA, long long strideB, long long strideC,
    const int* __restrict__ mExt, const int* __restrict__ nExt,
    const int* __restrict__ kDyn) {
  int b, bm, bn, k0beg, k0end;
  if constexpr (MODE == 0) {
    b = blockIdx.z; bm = blockIdx.y; bn = blockIdx.x;
    if (mExt && bm * 128 >= mExt[b]) return;
    if (nExt && bn * BN >= nExt[b]) return;
    k0beg = 0;
    k0end = kDyn ? kDyn[b] : Kfix;
  } else if constexpr (MODE == 1) {
    const int flat = blockIdx.x;                    // 1024 blocks
    const int logical = (flat & 7) * 128 + (flat >> 3);
    b = logical >> 7;
    const int rem = logical & 127;
    bm = rem >> 4; bn = rem & 15;
    if (nExt && bn * BN >= nExt[b]) return;
    k0beg = 0; k0end = Kfix;
  } else {
    const int flat = blockIdx.x;                    // 1024 blocks
    const int phys8 = flat & 7, rest = flat >> 3;   // rest in [0,128)
    const int chunk = phys8 + 8 * (rest >> 6);      // 16 chunks = (s, b)
    const int inner = rest & 63;
    b = chunk & 7;
    const int s = chunk >> 3;
    bm = inner >> 3; bn = inner & 7;
    const int K = kDyn[b], KH = K >> 1;             // K % 128 == 0 -> KH % 64 == 0
    k0beg = s * KH; k0end = k0beg + KH;
  }

  constexpr int NF = BN / 32;        // B fragments per wave
  __shared__ unsigned short As[128 * 32];
  __shared__ unsigned short Bs[BN * 32];
  const int tid = threadIdx.x;
  const int l = tid & 63, wid = tid >> 6;
  const int wr = wid >> 1, wc = wid & 1;

  const unsigned short* Abf = Ag + (size_t)b * strideA;
  const unsigned short* Bbf = Bg + (size_t)b * strideB;
  const int rowA0 = bm * 128, rowB0 = bn * BN;

  f32x4 acc[4][NF] = {};

  for (int k0 = k0beg; k0 < k0end; k0 += 32) {
    // A: 8 chunks of 1 KiB (16 rows x 32 k each); wave stages 2.
#pragma unroll
    for (int i = 0; i < 2; ++i) {
      const int c = wid * 2 + i;
      gload_lds16(Abf + (size_t)(rowA0 + c * 16 + (l >> 2)) * lda + k0 + (l & 3) * 8,
                  &As[c * 512]);
    }
    // B: BN/16 chunks; wave stages 2 (BN=128) or 1 (BN=64).
    if constexpr (BN == 128) {
#pragma unroll
      for (int i = 0; i < 2; ++i) {
        const int c = wid * 2 + i;
        gload_lds16(Bbf + (size_t)(rowB0 + c * 16 + (l >> 2)) * ldb + k0 + (l & 3) * 8,
                    &Bs[c * 512]);
      }
    } else {
      const int c = wid;
      gload_lds16(Bbf + (size_t)(rowB0 + c * 16 + (l >> 2)) * ldb + k0 + (l & 3) * 8,
                  &Bs[c * 512]);
    }
    __syncthreads();

    s16x8 af[4], bfr[NF];
#pragma unroll
    for (int m = 0; m < 4; ++m)
      af[m] = *(const s16x8*)&As[(wr * 64 + m * 16 + (l & 15)) * 32 + (l >> 4) * 8];
#pragma unroll
    for (int n = 0; n < NF; ++n)
      bfr[n] = *(const s16x8*)&Bs[(wc * (BN / 2) + n * 16 + (l & 15)) * 32 + (l >> 4) * 8];
#pragma unroll
    for (int m = 0; m < 4; ++m)
#pragma unroll
      for (int n = 0; n < NF; ++n)
        acc[m][n] = __builtin_amdgcn_mfma_f32_16x16x32_bf16(af[m], bfr[n], acc[m][n], 0, 0, 0);
    __syncthreads();
  }

  const int crow0 = bm * 128 + wr * 64, ccol0 = bn * BN + wc * (BN / 2);
  unsigned short* Cst = nullptr;
  float* Cf = nullptr;
  if constexpr (OUT_BF16)
    Cst = (unsigned short*)Cg_ + (size_t)b * strideC;
  else
    Cf = (float*)Cg_ + (size_t)b * strideC;
#pragma unroll
  for (int m = 0; m < 4; ++m) {
#pragma unroll
    for (int n = 0; n < NF; ++n) {
#pragma unroll
      for (int r = 0; r < 4; ++r) {
        const int row = crow0 + m * 16 + ((l >> 4) << 2) + r;
        const int col = ccol0 + n * 16 + (l & 15);
        const float val = acc[m][n][r] * scale;
        if constexpr (OUT_BF16) {
          Cst[(size_t)row * N + col] = f2bf(val);
        } else if constexpr (MODE == 2) {
          atomicAdd(&Cf[(size_t)row * N + col], val);  // 2 commutative f32 addends
        } else {
          Cf[(size_t)row * N + col] = val;
        }
      }
    }
  }
}

// Softmax over compacted cols [0, Lc); cols [Lc, Lcp) get exact 0.
__global__ __launch_bounds__(256) void softmax_c(
    unsigned short* __restrict__ S, const int* __restrict__ Lc,
    const int* __restrict__ Lcp) {
  const int row = blockIdx.x;  // b*T + t, T=1024
  const int b = row >> 10;
  unsigned short* Sr = S + (size_t)row * 2048;
  const int lc = Lc[b], lcp = Lcp[b];
  const int t = threadIdx.x;
  const int j0 = t * 8;
  const bool act = j0 < lcp;

  float v[8];
  if (act) {
    u16x8 raw = *(const u16x8*)(Sr + j0);
#pragma unroll
    for (int j = 0; j < 8; ++j) v[j] = (j0 + j < lc) ? bf2f(raw[j]) : -1.0e30f;
  } else {
#pragma unroll
    for (int j = 0; j < 8; ++j) v[j] = -1.0e30f;
  }

  float mx = -3.0e38f;
#pragma unroll
  for (int j = 0; j < 8; ++j) mx = fmaxf(mx, v[j]);
#pragma unroll
  for (int off = 32; off; off >>= 1) mx = fmaxf(mx, __shfl_xor(mx, off));
  __shared__ float redmx[4];
  __shared__ float redsm[4];
  if ((t & 63) == 0) redmx[t >> 6] = mx;
  __syncthreads();
  mx = fmaxf(fmaxf(redmx[0], redmx[1]), fmaxf(redmx[2], redmx[3]));

  float s = 0.f;
#pragma unroll
  for (int j = 0; j < 8; ++j) {
    v[j] = __expf(v[j] - mx);
    s += v[j];
  }
#pragma unroll
  for (int off = 32; off; off >>= 1) s += __shfl_xor(s, off);
  if ((t & 63) == 0) redsm[t >> 6] = s;
  __syncthreads();
  s = redsm[0] + redsm[1] + redsm[2] + redsm[3];
  const float inv = 1.0f / s;

  if (act) {
    u16x8 o;
#pragma unroll
    for (int j = 0; j < 8; ++j) o[j] = f2bf(v[j] * inv);
    *(u16x8*)(Sr + j0) = o;
  }
}

extern "C" void kernel_launch(void* const* d_in, const int* in_sizes, int n_in,
                              void* d_out, int out_size, void* d_ws, size_t ws_size,
                              hipStream_t stream) {
  const float* H  = (const float*)d_in[0];   // (B, L, Dh)
  const float* G  = (const float*)d_in[1];   // (B, T, Dg)
  const int* mask = (const int*)d_in[2];     // (B, L), nonzero = masked
  const float* Wk = (const float*)d_in[3];   // (P, Dh)
  const float* Wq = (const float*)d_in[4];   // (P, Dg)
  float* Z = (float*)d_out;                  // (B, T, Dh)

  const float SCALE = 0.0625f;  // 256^-0.5
  const size_t MiB = 1024 * 1024;

  char* ws = (char*)d_ws;
  unsigned short* HcT  = (unsigned short*)(ws);             // (B, Dh, L)  32 MiB
  unsigned short* Hc   = (unsigned short*)(ws + 32 * MiB);  // (B, L, Dh)  32 MiB
  unsigned short* Sbuf = Hc;  // alias: Hc dead after Kproj
  unsigned short* Kc   = (unsigned short*)(ws + 64 * MiB);  // (B, L, P)    8 MiB
  unsigned short* Qbuf = (unsigned short*)(ws + 72 * MiB);  // (B, T, P)    4 MiB
  int* idx = (int*)Qbuf;      // alias: idx dead before Qproj writes
  int* Lc  = (int*)(ws + 76 * MiB);
  int* Lcp = Lc + 16;
  unsigned short* Gbf  = (unsigned short*)(ws + 76 * MiB + 4096);  // 12 MiB
  unsigned short* Wkbf = (unsigned short*)(ws + 89 * MiB);         // 0.5 MiB
  unsigned short* Wqbf = (unsigned short*)(ws + 90 * MiB);         // 0.375 MiB

  // 0) zero Z (split-K atomics accumulate into it), scan, casts
  hipMemsetAsync(Z, 0, (size_t)out_size * sizeof(float), stream);
  mask_scan<<<dim3(8), 256, 0, stream>>>(mask, idx, Lc, Lcp);
  cast3_bf16<<<dim3(1024), 256, 0, stream>>>(
      G, Gbf, 8 * 1024 * 768 / 4, Wk, Wkbf, 256 * 1024 / 4, Wq, Wqbf, 256 * 768 / 4);

  // 1) gather unmasked H rows -> Hc + HcT (bf16), zero pad
  gather_cast<<<dim3(32, 16, 8), 256, 0, stream>>>(H, idx, Lc, Lcp, Hc, HcT);

  // 2) Kc = Hc @ Wk^T  (per batch: M = Lcp[b], N = 256, K = 1024)
  gemm_bt<64, true, 0><<<dim3(4, 16, 8), 256, 0, stream>>>(
      Hc, Wkbf, Kc, 256, 1024, 1024, 1024, 1.0f,
      (long long)2048 * 1024, 0, (long long)2048 * 256, Lcp, nullptr, nullptr);

  // 3) Q = G @ Wq^T  (M = 8192, N = 256, K = 768)
  gemm_bt<64, true, 0><<<dim3(4, 64, 1), 256, 0, stream>>>(
      Gbf, Wqbf, Qbuf, 256, 768, 768, 768, 1.0f, 0, 0, 0,
      nullptr, nullptr, nullptr);

  // 4) S = Q @ Kc^T * SCALE  (per batch: M = 1024, N = Lcp[b], K = 256)
  gemm_bt<128, true, 1><<<dim3(1024), 256, 0, stream>>>(
      Qbuf, Kc, Sbuf, 2048, 256, 256, 256, SCALE,
      (long long)1024 * 256, (long long)2048 * 256, (long long)1024 * 2048,
      nullptr, Lcp, nullptr);

  // 5) softmax over compacted cols, in place
  softmax_c<<<dim3(8 * 1024), 256, 0, stream>>>(Sbuf, Lc, Lcp);

  // 6) Z += alpha @ Hc  (per batch: M = 1024, N = 1024, K = Lcp[b]), split-K=2
  gemm_bt<128, false, 2><<<dim3(1024), 256, 0, stream>>>(
      Sbuf, HcT, Z, 1024, 0, 2048, 2048, 1.0f,
      (long long)1024 * 2048, (long long)1024 * 2048, (long long)1024 * 1024,
      nullptr, nullptr, Lcp);
}

// Round 5
// 121.154 us; speedup vs baseline: 1.3966x; 1.3966x over previous
//
#include <hip/hip_runtime.h>
#include <hip/hip_bf16.h>

typedef short s16x8 __attribute__((ext_vector_type(8)));
typedef float f32x4 __attribute__((ext_vector_type(4)));
typedef unsigned short u16x8 __attribute__((ext_vector_type(8)));

__device__ __forceinline__ unsigned short f2bf(float f) {
  union { __hip_bfloat16 h; unsigned short u; } cv;
  cv.h = __float2bfloat16(f);
  return cv.u;
}
__device__ __forceinline__ float bf2f(unsigned short u) {
  union { unsigned int i; float f; } cv;
  cv.i = ((unsigned int)u) << 16;
  return cv.f;
}

__device__ __forceinline__ void gload_lds16(const void* g, void* l) {
  __builtin_amdgcn_global_load_lds(
      (const __attribute__((address_space(1))) unsigned int*)g,
      (__attribute__((address_space(3))) unsigned int*)l,
      16, 0, 0);
}

// One-shot f32->bf16 cast of three buffers (G, Wk, Wq), float4-vectorized.
__global__ __launch_bounds__(256) void cast3_bf16(
    const float* __restrict__ a, unsigned short* __restrict__ da, int n4a,
    const float* __restrict__ b, unsigned short* __restrict__ db, int n4b,
    const float* __restrict__ c, unsigned short* __restrict__ dc, int n4c) {
  const int total = n4a + n4b + n4c;
  for (int i = blockIdx.x * 256 + threadIdx.x; i < total; i += gridDim.x * 256) {
    const float* s; unsigned short* d; int j = i;
    if (j < n4a) { s = a; d = da; }
    else if ((j -= n4a) < n4b) { s = b; d = db; }
    else { j -= n4b; s = c; d = dc; }
    float4 v = *(const float4*)(s + (size_t)j * 4);
    ushort4 o;
    o.x = f2bf(v.x); o.y = f2bf(v.y); o.z = f2bf(v.z); o.w = f2bf(v.w);
    *(ushort4*)(d + (size_t)j * 4) = o;
  }
}

// Per-batch compaction scan: keep[l] = (mask[l]==0).
__global__ __launch_bounds__(256) void mask_scan(
    const int* __restrict__ mask, int* __restrict__ idx,
    int* __restrict__ Lc, int* __restrict__ Lcp) {
  const int b = blockIdx.x;
  const int* mb = mask + (size_t)b * 2048;
  int* ib = idx + (size_t)b * 2048;
  const int t = threadIdx.x;
  __shared__ int tot[256];
  __shared__ int off[257];
  int keep[8], cnt = 0;
#pragma unroll
  for (int j = 0; j < 8; ++j) {
    keep[j] = (mb[t * 8 + j] == 0);
    cnt += keep[j];
  }
  tot[t] = cnt;
  __syncthreads();
  if (t == 0) {
    int s = 0;
    for (int i = 0; i < 256; ++i) { off[i] = s; s += tot[i]; }
    off[256] = s;
  }
  __syncthreads();
  int p = off[t];
#pragma unroll
  for (int j = 0; j < 8; ++j)
    if (keep[j]) ib[p++] = t * 8 + j;
  if (t == 0) {
    Lc[b] = off[256];
    Lcp[b] = (off[256] + 127) & ~127;
  }
}

// Gather unmasked H rows (f32) -> Hc (B, L, Dh) bf16 row-major AND
// HcT (B, Dh, L) bf16 transposed. Rows [Lc, Lcp) zero-filled.
__global__ __launch_bounds__(256) void gather_cast(
    const float* __restrict__ H, const int* __restrict__ idx,
    const int* __restrict__ Lc, const int* __restrict__ Lcp,
    unsigned short* __restrict__ Hc, unsigned short* __restrict__ HcT) {
  const int b = blockIdx.z;
  const int j0 = blockIdx.x * 64, d0 = blockIdx.y * 64;
  if (j0 >= Lcp[b]) return;
  const int lc = Lc[b];
  __shared__ unsigned short tile[64][72];
  const int t = threadIdx.x;

  const int r = t >> 2, dc = (t & 3) * 16;
  const int j = j0 + r;
  const int src = (j < lc) ? idx[(size_t)b * 2048 + j] : -1;
  ushort4 s[4];
  if (src >= 0) {
    const float* p = H + ((size_t)b * 2048 + src) * 1024 + d0 + dc;
#pragma unroll
    for (int i = 0; i < 4; ++i) {
      float4 v = *(const float4*)(p + 4 * i);
      s[i].x = f2bf(v.x); s[i].y = f2bf(v.y); s[i].z = f2bf(v.z); s[i].w = f2bf(v.w);
    }
  } else {
#pragma unroll
    for (int i = 0; i < 4; ++i) { s[i].x = 0; s[i].y = 0; s[i].z = 0; s[i].w = 0; }
  }
  unsigned short* hcrow = Hc + ((size_t)b * 2048 + j) * 1024 + d0 + dc;
#pragma unroll
  for (int i = 0; i < 4; ++i) {
    *(ushort4*)&tile[r][dc + 4 * i] = s[i];
    *(ushort4*)(hcrow + 4 * i) = s[i];
  }
  __syncthreads();

  const int dr = t >> 2, lcc = (t & 3) * 16;
  unsigned short o[16];
#pragma unroll
  for (int i = 0; i < 16; ++i) o[i] = tile[lcc + i][dr];
  unsigned short* dst = HcT + ((size_t)b * 1024 + d0 + dr) * 2048 + j0 + lcc;
  *(uint4*)dst = *(uint4*)&o[0];
  *(uint4*)(dst + 8) = *(uint4*)&o[8];
}

// C (M x N tile 128 x BN) = A (M x K) * B^T, bf16 in via global_load_lds.
// MODE 0: plain 3D grid (x=bn, y=bm, z=b).
// MODE 1: batched XCD-chunk swizzle. 1D grid of 8*NBM*NBN; batch = flat&7
//         (one batch per XCD), inner = flat>>3, bm = inner/NBN, bn = inner%NBN.
// MODE 2: single-matrix XCD-chunk swizzle. 1D grid of NBM*NBN; each XCD gets
//         a contiguous 1/8 chunk of the logical grid.
template <int BN, bool OUT_BF16, int MODE, int NBN>
__global__ __launch_bounds__(256) void gemm_bt(
    const unsigned short* __restrict__ Ag, const unsigned short* __restrict__ Bg,
    void* __restrict__ Cg_, int N, int Kfix, int lda, int ldb, float scale,
    long long strideA, long long strideB, long long strideC,
    const int* __restrict__ mExt, const int* __restrict__ nExt,
    const int* __restrict__ kDyn) {
  int b, bm, bn;
  if constexpr (MODE == 0) {
    b = blockIdx.z; bm = blockIdx.y; bn = blockIdx.x;
  } else if constexpr (MODE == 1) {
    b = blockIdx.x & 7;
    const int inner = blockIdx.x >> 3;
    bm = inner / NBN; bn = inner % NBN;
  } else {
    const int cs = gridDim.x >> 3;
    const int logical = (blockIdx.x & 7) * cs + (blockIdx.x >> 3);
    b = 0; bm = logical / NBN; bn = logical % NBN;
  }
  if (mExt && bm * 128 >= mExt[b]) return;
  if (nExt && bn * BN >= nExt[b]) return;
  const int K = kDyn ? kDyn[b] : Kfix;

  constexpr int NF = BN / 32;        // B fragments per wave
  __shared__ unsigned short As[128 * 32];
  __shared__ unsigned short Bs[BN * 32];
  const int tid = threadIdx.x;
  const int l = tid & 63, wid = tid >> 6;
  const int wr = wid >> 1, wc = wid & 1;

  const unsigned short* Abf = Ag + (size_t)b * strideA;
  const unsigned short* Bbf = Bg + (size_t)b * strideB;
  const int rowA0 = bm * 128, rowB0 = bn * BN;

  f32x4 acc[4][NF] = {};

  for (int k0 = 0; k0 < K; k0 += 32) {
    // A: 8 chunks of 1 KiB (16 rows x 32 k each); wave stages 2.
#pragma unroll
    for (int i = 0; i < 2; ++i) {
      const int c = wid * 2 + i;
      gload_lds16(Abf + (size_t)(rowA0 + c * 16 + (l >> 2)) * lda + k0 + (l & 3) * 8,
                  &As[c * 512]);
    }
    // B: BN/16 chunks; wave stages 2 (BN=128) or 1 (BN=64).
    if constexpr (BN == 128) {
#pragma unroll
      for (int i = 0; i < 2; ++i) {
        const int c = wid * 2 + i;
        gload_lds16(Bbf + (size_t)(rowB0 + c * 16 + (l >> 2)) * ldb + k0 + (l & 3) * 8,
                    &Bs[c * 512]);
      }
    } else {
      const int c = wid;
      gload_lds16(Bbf + (size_t)(rowB0 + c * 16 + (l >> 2)) * ldb + k0 + (l & 3) * 8,
                  &Bs[c * 512]);
    }
    __syncthreads();

    s16x8 af[4], bfr[NF];
#pragma unroll
    for (int m = 0; m < 4; ++m)
      af[m] = *(const s16x8*)&As[(wr * 64 + m * 16 + (l & 15)) * 32 + (l >> 4) * 8];
#pragma unroll
    for (int n = 0; n < NF; ++n)
      bfr[n] = *(const s16x8*)&Bs[(wc * (BN / 2) + n * 16 + (l & 15)) * 32 + (l >> 4) * 8];
#pragma unroll
    for (int m = 0; m < 4; ++m)
#pragma unroll
      for (int n = 0; n < NF; ++n)
        acc[m][n] = __builtin_amdgcn_mfma_f32_16x16x32_bf16(af[m], bfr[n], acc[m][n], 0, 0, 0);
    __syncthreads();
  }

  const int crow0 = bm * 128 + wr * 64, ccol0 = bn * BN + wc * (BN / 2);
  unsigned short* Cst = nullptr;
  float* Cf = nullptr;
  if constexpr (OUT_BF16)
    Cst = (unsigned short*)Cg_ + (size_t)b * strideC;
  else
    Cf = (float*)Cg_ + (size_t)b * strideC;
#pragma unroll
  for (int m = 0; m < 4; ++m) {
#pragma unroll
    for (int n = 0; n < NF; ++n) {
#pragma unroll
      for (int r = 0; r < 4; ++r) {
        const int row = crow0 + m * 16 + ((l >> 4) << 2) + r;
        const int col = ccol0 + n * 16 + (l & 15);
        const float val = acc[m][n][r] * scale;
        if constexpr (OUT_BF16)
          Cst[(size_t)row * N + col] = f2bf(val);
        else
          Cf[(size_t)row * N + col] = val;
      }
    }
  }
}

// Softmax over compacted cols [0, Lc); cols [Lc, Lcp) get exact 0.
__global__ __launch_bounds__(256) void softmax_c(
    unsigned short* __restrict__ S, const int* __restrict__ Lc,
    const int* __restrict__ Lcp) {
  const int row = blockIdx.x;  // b*T + t, T=1024
  const int b = row >> 10;
  unsigned short* Sr = S + (size_t)row * 2048;
  const int lc = Lc[b], lcp = Lcp[b];
  const int t = threadIdx.x;
  const int j0 = t * 8;
  const bool act = j0 < lcp;

  float v[8];
  if (act) {
    u16x8 raw = *(const u16x8*)(Sr + j0);
#pragma unroll
    for (int j = 0; j < 8; ++j) v[j] = (j0 + j < lc) ? bf2f(raw[j]) : -1.0e30f;
  } else {
#pragma unroll
    for (int j = 0; j < 8; ++j) v[j] = -1.0e30f;
  }

  float mx = -3.0e38f;
#pragma unroll
  for (int j = 0; j < 8; ++j) mx = fmaxf(mx, v[j]);
#pragma unroll
  for (int off = 32; off; off >>= 1) mx = fmaxf(mx, __shfl_xor(mx, off));
  __shared__ float redmx[4];
  __shared__ float redsm[4];
  if ((t & 63) == 0) redmx[t >> 6] = mx;
  __syncthreads();
  mx = fmaxf(fmaxf(redmx[0], redmx[1]), fmaxf(redmx[2], redmx[3]));

  float s = 0.f;
#pragma unroll
  for (int j = 0; j < 8; ++j) {
    v[j] = __expf(v[j] - mx);
    s += v[j];
  }
#pragma unroll
  for (int off = 32; off; off >>= 1) s += __shfl_xor(s, off);
  if ((t & 63) == 0) redsm[t >> 6] = s;
  __syncthreads();
  s = redsm[0] + redsm[1] + redsm[2] + redsm[3];
  const float inv = 1.0f / s;

  if (act) {
    u16x8 o;
#pragma unroll
    for (int j = 0; j < 8; ++j) o[j] = f2bf(v[j] * inv);
    *(u16x8*)(Sr + j0) = o;
  }
}

extern "C" void kernel_launch(void* const* d_in, const int* in_sizes, int n_in,
                              void* d_out, int out_size, void* d_ws, size_t ws_size,
                              hipStream_t stream) {
  const float* H  = (const float*)d_in[0];   // (B, L, Dh)
  const float* G  = (const float*)d_in[1];   // (B, T, Dg)
  const int* mask = (const int*)d_in[2];     // (B, L), nonzero = masked
  const float* Wk = (const float*)d_in[3];   // (P, Dh)
  const float* Wq = (const float*)d_in[4];   // (P, Dg)
  float* Z = (float*)d_out;                  // (B, T, Dh)

  const float SCALE = 0.0625f;  // 256^-0.5
  const size_t MiB = 1024 * 1024;

  char* ws = (char*)d_ws;
  unsigned short* HcT  = (unsigned short*)(ws);             // (B, Dh, L)  32 MiB
  unsigned short* Hc   = (unsigned short*)(ws + 32 * MiB);  // (B, L, Dh)  32 MiB
  unsigned short* Sbuf = Hc;  // alias: Hc dead after Kproj
  unsigned short* Kc   = (unsigned short*)(ws + 64 * MiB);  // (B, L, P)    8 MiB
  unsigned short* Qbuf = (unsigned short*)(ws + 72 * MiB);  // (B, T, P)    4 MiB
  int* idx = (int*)Qbuf;      // alias: idx dead before Qproj writes
  int* Lc  = (int*)(ws + 76 * MiB);
  int* Lcp = Lc + 16;
  unsigned short* Gbf  = (unsigned short*)(ws + 76 * MiB + 4096);  // 12 MiB
  unsigned short* Wkbf = (unsigned short*)(ws + 89 * MiB);         // 0.5 MiB
  unsigned short* Wqbf = (unsigned short*)(ws + 90 * MiB);         // 0.375 MiB

  // 0) scan + casts
  mask_scan<<<dim3(8), 256, 0, stream>>>(mask, idx, Lc, Lcp);
  cast3_bf16<<<dim3(1024), 256, 0, stream>>>(
      G, Gbf, 8 * 1024 * 768 / 4, Wk, Wkbf, 256 * 1024 / 4, Wq, Wqbf, 256 * 768 / 4);

  // 1) gather unmasked H rows -> Hc + HcT (bf16), zero pad
  gather_cast<<<dim3(32, 16, 8), 256, 0, stream>>>(H, idx, Lc, Lcp, Hc, HcT);

  // 2) Kc = Hc @ Wk^T  (per batch: M = Lcp[b], N = 256, K = 1024)
  //    batched swizzle: NBM=16, NBN=4 -> 8*64 = 512 blocks
  gemm_bt<64, true, 1, 4><<<dim3(512), 256, 0, stream>>>(
      Hc, Wkbf, Kc, 256, 1024, 1024, 1024, 1.0f,
      (long long)2048 * 1024, 0, (long long)2048 * 256, Lcp, nullptr, nullptr);

  // 3) Q = G @ Wq^T  (M = 8192, N = 256, K = 768); single swizzle NBM=64 NBN=4
  gemm_bt<64, true, 2, 4><<<dim3(256), 256, 0, stream>>>(
      Gbf, Wqbf, Qbuf, 256, 768, 768, 768, 1.0f, 0, 0, 0,
      nullptr, nullptr, nullptr);

  // 4) S = Q @ Kc^T * SCALE  (per batch: M = 1024, N = Lcp[b], K = 256)
  //    batched swizzle: NBM=8, NBN=16 -> 1024 blocks
  gemm_bt<128, true, 1, 16><<<dim3(1024), 256, 0, stream>>>(
      Qbuf, Kc, Sbuf, 2048, 256, 256, 256, SCALE,
      (long long)1024 * 256, (long long)2048 * 256, (long long)1024 * 2048,
      nullptr, Lcp, nullptr);

  // 5) softmax over compacted cols, in place
  softmax_c<<<dim3(8 * 1024), 256, 0, stream>>>(Sbuf, Lc, Lcp);

  // 6) Z = alpha @ Hc  (per batch: M = 1024, N = 1024, K = Lcp[b])
  //    128x64 tiles: NBM=8, NBN=16 -> 1024 blocks (4 blocks/CU)
  gemm_bt<64, false, 1, 16><<<dim3(1024), 256, 0, stream>>>(
      Sbuf, HcT, Z, 1024, 0, 2048, 2048, 1.0f,
      (long long)1024 * 2048, (long long)1024 * 2048, (long long)1024 * 1024,
      nullptr, nullptr, Lcp);
}